// Round 2
// baseline (20.221 us; speedup 1.0000x reference)
//
#include <hip/hip_runtime.h>
#include <hip/hip_bf16.h>

// out[b,k] = relu( sum_d (obs*mask)[b,d]*G[d,k] + s1[b]*W[10,k] + s0[b]*bw[k] )
// G[d,k] = sum_f F[d,f]*W[f,k];  s0[b]=sum_d mask;  s1[b]=sum_d mask*bvec[d]
// B=4096, D=512, K=64.

#define D_DIM 512
#define K_DIM 64
#define B_DIM 4096

__global__ void prep_G_kernel(const float* __restrict__ F,
                              const float* __restrict__ W,
                              float* __restrict__ G) {
    int i = blockIdx.x * blockDim.x + threadIdx.x;   // 0 .. 512*64-1
    int d = i >> 6;
    int k = i & 63;
    float s = 0.f;
#pragma unroll
    for (int f = 0; f < 10; ++f)
        s = fmaf(F[d * 10 + f], W[f * 64 + k], s);
    G[i] = s;
}

// 256 blocks (1 per CU), 512 threads (8 waves), 16 rows/block in 2 batches of 8.
// Wave w owns d-slice [64w, 64w+64) with G in registers; lane l = output k.
// Batch pipeline: batch1 global loads are issued into registers BEFORE the
// batch0 FMA phase; register destinations cross barriers without vmcnt drain.
__global__ __launch_bounds__(512, 2)
void main_kernel(const float* __restrict__ obs,
                 const float* __restrict__ mask,
                 const float* __restrict__ bvec,
                 const float* __restrict__ W,
                 const float* __restrict__ bw,
                 const float* __restrict__ G,
                 float* __restrict__ out) {
    __shared__ float Xs[2][8][D_DIM];      // 32 KB: two batches of 8 X-rows
    __shared__ float part[8][8][K_DIM];    // 16 KB: [row][wave][k] partials
    __shared__ float s0s[2][8], s1s[2][8];

    const int tid = threadIdx.x;
    const int w   = tid >> 6;     // wave 0..7 = d-slice
    const int l   = tid & 63;     // lane = k
    const int rowbase = blockIdx.x * 16;
    const int dbase = w * 64;

    // ---- G slice into registers (L2-resident after first blocks) ----
    float g[64];
#pragma unroll
    for (int j = 0; j < 64; ++j)
        g[j] = G[(dbase + j) * K_DIM + l];

    // bvec chunks for staging (lane covers d = 4l..4l+3 and +256)
    const float4 bv0 = *reinterpret_cast<const float4*>(&bvec[4 * l]);
    const float4 bv1 = *reinterpret_cast<const float4*>(&bvec[4 * l + 256]);
    const float w10 = W[10 * K_DIM + l];
    const float bwv = bw[l];

    float4 o0, o1, m0, m1;   // staging registers (reused per batch)

    auto issue_loads = [&](int b) {
        const size_t base = (size_t)(rowbase + b * 8 + w) * D_DIM + 4 * l;
        o0 = *reinterpret_cast<const float4*>(obs  + base);
        o1 = *reinterpret_cast<const float4*>(obs  + base + 256);
        m0 = *reinterpret_cast<const float4*>(mask + base);
        m1 = *reinterpret_cast<const float4*>(mask + base + 256);
    };

    auto finish_stage = [&](int b) {
        float4 x0, x1;
        x0.x = o0.x * m0.x; x0.y = o0.y * m0.y; x0.z = o0.z * m0.z; x0.w = o0.w * m0.w;
        x1.x = o1.x * m1.x; x1.y = o1.y * m1.y; x1.z = o1.z * m1.z; x1.w = o1.w * m1.w;
        *reinterpret_cast<float4*>(&Xs[b][w][4 * l])       = x0;
        *reinterpret_cast<float4*>(&Xs[b][w][4 * l + 256]) = x1;
        float p0 = (m0.x + m0.y) + (m0.z + m0.w) + (m1.x + m1.y) + (m1.z + m1.w);
        float p1 = m0.x * bv0.x + m0.y * bv0.y + m0.z * bv0.z + m0.w * bv0.w
                 + m1.x * bv1.x + m1.y * bv1.y + m1.z * bv1.z + m1.w * bv1.w;
#pragma unroll
        for (int s = 1; s < 64; s <<= 1) {
            p0 += __shfl_xor(p0, s, 64);
            p1 += __shfl_xor(p1, s, 64);
        }
        if (l == 0) { s0s[b][w] = p0; s1s[b][w] = p1; }
    };

    float acc[8];
    auto fma_batch = [&](int b) {
#pragma unroll
        for (int r = 0; r < 8; ++r) acc[r] = 0.f;
#pragma unroll
        for (int j = 0; j < 64; j += 4) {
#pragma unroll
            for (int r = 0; r < 8; ++r) {
                float4 xv = *reinterpret_cast<const float4*>(&Xs[b][r][dbase + j]);
                acc[r] = fmaf(xv.x, g[j + 0], acc[r]);
                acc[r] = fmaf(xv.y, g[j + 1], acc[r]);
                acc[r] = fmaf(xv.z, g[j + 2], acc[r]);
                acc[r] = fmaf(xv.w, g[j + 3], acc[r]);
            }
        }
#pragma unroll
        for (int r = 0; r < 8; ++r) part[r][w][l] = acc[r];
    };

    auto combine_store = [&](int b) {
        float total = 0.f;
#pragma unroll
        for (int ww = 0; ww < 8; ++ww) total += part[w][ww][l];
        total = fmaf(s1s[b][w], w10, total);
        total = fmaf(s0s[b][w], bwv, total);
        out[(size_t)(rowbase + b * 8 + w) * K_DIM + l] = fmaxf(total, 0.f);
    };

    // ---- pipeline ----
    issue_loads(0);
    finish_stage(0);
    __syncthreads();                 // Xs[0] ready

    issue_loads(1);                  // batch1 HBM loads in flight under FMA(0)
    fma_batch(0);
    __syncthreads();                 // part(0) ready; Xs[0] reads done

    finish_stage(1);                 // lands batch1 into Xs[1]
    combine_store(0);                // reads part(0) before it is reused
    __syncthreads();                 // Xs[1] ready; part free

    fma_batch(1);
    __syncthreads();                 // part(1) ready

    combine_store(1);
}

extern "C" void kernel_launch(void* const* d_in, const int* in_sizes, int n_in,
                              void* d_out, int out_size, void* d_ws, size_t ws_size,
                              hipStream_t stream) {
    const float* obs  = (const float*)d_in[0];  // [4096, 512]
    const float* mask = (const float*)d_in[1];  // [4096, 512]
    const float* F    = (const float*)d_in[2];  // [1, 512, 10]
    const float* bvec = (const float*)d_in[3];  // [1, 512, 1]
    const float* W    = (const float*)d_in[4];  // [11, 64]
    const float* bw   = (const float*)d_in[5];  // [64]
    float* out = (float*)d_out;                 // [4096, 64]
    float* G   = (float*)d_ws;                  // [512, 64]

    prep_G_kernel<<<(D_DIM * K_DIM) / 256, 256, 0, stream>>>(F, W, G);
    main_kernel<<<B_DIM / 16, 512, 0, stream>>>(obs, mask, bvec, W, bw, G, out);
}

// Round 3
// 12.967 us; speedup vs baseline: 1.5594x; 1.5594x over previous
//
#include <hip/hip_runtime.h>
#include <hip/hip_bf16.h>

// out[b,k] = relu( sum_d (obs*mask)[b,d]*G[d,k] + s1[b]*W[10,k] + s0[b]*bw[k] )
// G[d,k] = sum_f F[d,f]*W[f,k];  s0[b]=sum_d mask;  s1[b]=sum_d mask*bvec[d]
// B=4096, D=512, K=64.
// GEMM X[4096x512]@G[512x64] done in bf16 MFMA (validation threshold 1.64 >>
// bf16 error ~0.05); s0/s1/epilogue kept in fp32.

#define D_DIM 512
#define K_DIM 64
#define B_DIM 4096

typedef __attribute__((ext_vector_type(4))) float f32x4;
typedef __attribute__((ext_vector_type(8))) short bf16x8;

__device__ __forceinline__ unsigned short f2bf(float f) {
    unsigned u = __builtin_bit_cast(unsigned, f);
    u += 0x7fffu + ((u >> 16) & 1u);          // RNE
    return (unsigned short)(u >> 16);
}

// Gf fragment tensor: Gf[w][tp][lane][j] (bf16), w=wave 0..7, tp=k-step 0..7.
// Element = G[d][n], d = (w>>2)*256 + tp*32 + (lane>>4)*8 + j,
//                    n = (w&3)*16 + (lane&15).
__global__ void prep_Gf_kernel(const float* __restrict__ F,
                               const float* __restrict__ W,
                               unsigned short* __restrict__ Gf) {
    int i = blockIdx.x * blockDim.x + threadIdx.x;  // 0..4095
    int lane = i & 63;
    int tp   = (i >> 6) & 7;
    int w    = i >> 9;
    int n     = (w & 3) * 16 + (lane & 15);
    int dbase = (w >> 2) * 256 + tp * 32 + (lane >> 4) * 8;
    unsigned short v[8];
#pragma unroll
    for (int j = 0; j < 8; ++j) {
        int d = dbase + j;
        float s = 0.f;
#pragma unroll
        for (int f = 0; f < 10; ++f)
            s = fmaf(F[d * 10 + f], W[f * 64 + n], s);
        v[j] = f2bf(s);
    }
    *reinterpret_cast<ushort4*>(Gf + (size_t)i * 8)     = make_ushort4(v[0], v[1], v[2], v[3]);
    *reinterpret_cast<ushort4*>(Gf + (size_t)i * 8 + 4) = make_ushort4(v[4], v[5], v[6], v[7]);
}

// 256 blocks x 512 threads (8 waves). Block = 16 rows x 64 k, full D=512.
// Wave w: n-group (w&3) of 16 k's, d-half (w>>2); 8 MFMA steps of 32 d.
// X staged in LDS bf16 [16][512] with 16B-slot XOR swizzle byte^=((row&7)<<4).
__global__ __launch_bounds__(512, 2)
void main_kernel(const float* __restrict__ obs,
                 const float* __restrict__ mask,
                 const float* __restrict__ bvec,
                 const float* __restrict__ W,
                 const float* __restrict__ bw,
                 const unsigned short* __restrict__ Gf,
                 float* __restrict__ out) {
    __shared__ __align__(16) unsigned short Xs[16 * 512];  // 16 KB
    __shared__ float part[8][64][4];                       // 8 KB
    __shared__ float s0s[16], s1s[16];

    const int tid  = threadIdx.x;
    const int lane = tid & 63;
    const int w    = tid >> 6;
    const int rowbase = blockIdx.x * 16;

    // ---- preload this wave's G fragments (64 KB total, L2-resident) ----
    bf16x8 gfr[8];
#pragma unroll
    for (int tp = 0; tp < 8; ++tp)
        gfr[tp] = *reinterpret_cast<const bf16x8*>(
            Gf + ((size_t)(w * 8 + tp) * 64 + lane) * 8);

    // epilogue constants (per-lane k)
    const int kk = (w & 3) * 16 + (lane & 15);
    const float w10 = W[10 * K_DIM + kk];
    const float bwv = bw[kk];

    // ---- stage: X -> LDS bf16 (swizzled), s0/s1 row reductions ----
    {
        const int r = tid >> 5;       // row 0..15 (32 threads per row)
        const int c = tid & 31;
        const float* orow = obs  + (size_t)(rowbase + r) * D_DIM;
        const float* mrow = mask + (size_t)(rowbase + r) * D_DIM;
        f32x4 o[4], m[4], bv[4];
#pragma unroll
        for (int j = 0; j < 4; ++j) {
            int d = c * 4 + 128 * j;
            o[j]  = *reinterpret_cast<const f32x4*>(orow + d);
            m[j]  = *reinterpret_cast<const f32x4*>(mrow + d);
            bv[j] = *reinterpret_cast<const f32x4*>(bvec + d);
        }
        float p0 = 0.f, p1 = 0.f;
        const int swz = (r & 7) << 4;
        char* xb = reinterpret_cast<char*>(Xs);
#pragma unroll
        for (int j = 0; j < 4; ++j) {
            ushort4 pk;
            pk.x = f2bf(o[j].x * m[j].x);
            pk.y = f2bf(o[j].y * m[j].y);
            pk.z = f2bf(o[j].z * m[j].z);
            pk.w = f2bf(o[j].w * m[j].w);
            int byteoff = r * 1024 + ((c * 8 + 256 * j) ^ swz);
            *reinterpret_cast<ushort4*>(xb + byteoff) = pk;
            p0 += (m[j].x + m[j].y) + (m[j].z + m[j].w);
            p1 = fmaf(m[j].x, bv[j].x, p1);
            p1 = fmaf(m[j].y, bv[j].y, p1);
            p1 = fmaf(m[j].z, bv[j].z, p1);
            p1 = fmaf(m[j].w, bv[j].w, p1);
        }
#pragma unroll
        for (int s = 1; s <= 16; s <<= 1) {   // reduce within 32-lane row-group
            p0 += __shfl_xor(p0, s, 64);
            p1 += __shfl_xor(p1, s, 64);
        }
        if (c == 0) { s0s[r] = p0; s1s[r] = p1; }
    }
    __syncthreads();

    // ---- MFMA: 8 steps of K=32 over this wave's d-half ----
    f32x4 acc = {0.f, 0.f, 0.f, 0.f};
    {
        const int row = lane & 15;
        const int g   = lane >> 4;
        const int swz = (row & 7) << 4;
        const int h   = w >> 2;
        const char* xb = reinterpret_cast<const char*>(Xs);
#pragma unroll
        for (int tp = 0; tp < 8; ++tp) {
            int byteoff = row * 1024 + ((512 * h + 64 * tp + 16 * g) ^ swz);
            bf16x8 a = *reinterpret_cast<const bf16x8*>(xb + byteoff);
            acc = __builtin_amdgcn_mfma_f32_16x16x32_bf16(a, gfr[tp], acc, 0, 0, 0);
        }
    }

    // ---- combine d-halves, epilogue, store ----
#pragma unroll
    for (int r = 0; r < 4; ++r) part[w][lane][r] = acc[r];
    __syncthreads();

    if (w < 4) {
        const int g = lane >> 4;
#pragma unroll
        for (int r = 0; r < 4; ++r) {
            const int rowl = g * 4 + r;              // C/D: row=(lane>>4)*4+reg
            float tot = part[w][lane][r] + part[w + 4][lane][r];
            tot = fmaf(s1s[rowl], w10, tot);
            tot = fmaf(s0s[rowl], bwv, tot);
            out[(size_t)(rowbase + rowl) * K_DIM + kk] = fmaxf(tot, 0.f);
        }
    }
}

extern "C" void kernel_launch(void* const* d_in, const int* in_sizes, int n_in,
                              void* d_out, int out_size, void* d_ws, size_t ws_size,
                              hipStream_t stream) {
    const float* obs  = (const float*)d_in[0];  // [4096, 512]
    const float* mask = (const float*)d_in[1];  // [4096, 512]
    const float* F    = (const float*)d_in[2];  // [1, 512, 10]
    const float* bvec = (const float*)d_in[3];  // [1, 512, 1]
    const float* W    = (const float*)d_in[4];  // [11, 64]
    const float* bw   = (const float*)d_in[5];  // [64]
    float* out = (float*)d_out;                 // [4096, 64]
    unsigned short* Gf = (unsigned short*)d_ws; // 32768 bf16 = 64 KB

    prep_Gf_kernel<<<16, 256, 0, stream>>>(F, W, Gf);
    main_kernel<<<B_DIM / 16, 512, 0, stream>>>(obs, mask, bvec, W, bw, Gf, out);
}